// Round 1
// baseline (2724.122 us; speedup 1.0000x reference)
//
#include <hip/hip_runtime.h>
#include <cmath>

// ---------------------------------------------------------------------------
// MoEProjector: router(softmax,top2) -> per-expert [Linear -> GELU -> Linear]
// -> gate-weighted combine -> *gate_scale -> LayerNorm.
// Shapes: T=8192 tokens, D=1024, O=4096, E=4 experts.
// Strategy: bf16 MFMA GEMMs (m97 structure: 128x128 tile, BK=32,
// global_load_lds width=16), fp32 router + LN for exactness.
// ---------------------------------------------------------------------------

typedef float f32x4 __attribute__((ext_vector_type(4)));
typedef __bf16 bf16x8 __attribute__((ext_vector_type(8)));
typedef __bf16 bf16x4 __attribute__((ext_vector_type(4)));

#define T_TOK 8192
#define DDIM 1024
#define ODIM 4096
#define NEXP 4

__device__ __forceinline__ void gl_lds16(const void* g, void* l) {
    __builtin_amdgcn_global_load_lds(
        (const __attribute__((address_space(1))) void*)g,
        (__attribute__((address_space(3))) void*)l, 16, 0, 0);
}

// ---------------- x fp32 -> bf16 (vectorized) ----------------
__global__ __launch_bounds__(256) void cvt_bf16_vec(const float* __restrict__ in,
                                                    __bf16* __restrict__ out, int n4) {
    int i = blockIdx.x * 256 + threadIdx.x;
    if (i >= n4) return;
    float4 v = ((const float4*)in)[i];
    bf16x4 o = { (__bf16)v.x, (__bf16)v.y, (__bf16)v.z, (__bf16)v.w };
    ((bf16x4*)out)[i] = o;
}

// ------------- W [R,C] fp32 -> Wt [C,R] bf16, per expert (z) -------------
__global__ __launch_bounds__(256) void transpose_cvt(const float* __restrict__ in,
                                                     __bf16* __restrict__ out,
                                                     int R, int C) {
    __shared__ float tile[32][33];
    const size_t eoff = (size_t)blockIdx.z * R * C;
    const float* ip = in + eoff;
    __bf16* op = out + eoff;
    const int c0 = blockIdx.x * 32, r0 = blockIdx.y * 32;
    const int tx = threadIdx.x, ty = threadIdx.y;  // 32 x 8
#pragma unroll
    for (int i = 0; i < 4; i++)
        tile[ty + i * 8][tx] = ip[(size_t)(r0 + ty + i * 8) * C + c0 + tx];
    __syncthreads();
#pragma unroll
    for (int i = 0; i < 4; i++)
        op[(size_t)(c0 + ty + i * 8) * R + r0 + tx] = (__bf16)tile[tx][ty + i * 8];
}

// ---------------- router: fp32 logits -> softmax -> top2 -> gates[T,4] -----
__global__ __launch_bounds__(256) void router_kernel(const float* __restrict__ x,
                                                     const float* __restrict__ Wg,
                                                     const float* __restrict__ bg,
                                                     float* __restrict__ gates) {
    const int wave = threadIdx.x >> 6, lane = threadIdx.x & 63;
    const int t = blockIdx.x * 4 + wave;
    const float* xr = x + (size_t)t * DDIM;
    float a0 = 0.f, a1 = 0.f, a2 = 0.f, a3 = 0.f;
    const float4* Wg4 = (const float4*)Wg;  // Wg[d*4 + e] contiguous over e
    for (int d = lane; d < DDIM; d += 64) {
        float xv = xr[d];
        float4 w = Wg4[d];
        a0 += xv * w.x; a1 += xv * w.y; a2 += xv * w.z; a3 += xv * w.w;
    }
#pragma unroll
    for (int off = 32; off; off >>= 1) {
        a0 += __shfl_xor(a0, off); a1 += __shfl_xor(a1, off);
        a2 += __shfl_xor(a2, off); a3 += __shfl_xor(a3, off);
    }
    if (lane == 0) {
        float l[4] = {a0 + bg[0], a1 + bg[1], a2 + bg[2], a3 + bg[3]};
        float mx = fmaxf(fmaxf(l[0], l[1]), fmaxf(l[2], l[3]));
        float p[4], s = 0.f;
#pragma unroll
        for (int e = 0; e < 4; e++) { p[e] = expf(l[e] - mx); s += p[e]; }
#pragma unroll
        for (int e = 0; e < 4; e++) p[e] /= s;
        int e1 = 0;  // argmax, lowest index on ties (strict >)
#pragma unroll
        for (int e = 1; e < 4; e++) if (p[e] > p[e1]) e1 = e;
        int e2 = (e1 == 0) ? 1 : 0;
#pragma unroll
        for (int e = 0; e < 4; e++) if (e != e1 && p[e] > p[e2]) e2 = e;
        float wsum = p[e1] + p[e2];
        float g[4] = {0.f, 0.f, 0.f, 0.f};
        g[e1] = p[e1] / wsum;
        g[e2] = p[e2] / wsum;
        float4 gv = {g[0], g[1], g[2], g[3]};
        ((float4*)gates)[t] = gv;
    }
}

// ---------------- GEMM C[M,N] = A[M,K] @ B^T[N,K]  (bf16 in, fp32 acc) -----
// MODE 0: H = gelu_erf(acc + b1)  -> bf16, row stride ODIM
// MODE 1: out (+)= gate * (acc + b2) -> fp32, row stride ODIM
template <int MODE>
__global__ __launch_bounds__(256) void moe_gemm(const __bf16* __restrict__ A,
                                                const __bf16* __restrict__ B, int K,
                                                const float* __restrict__ bias,
                                                __bf16* __restrict__ Hout,
                                                float* __restrict__ Fout,
                                                const float* __restrict__ gates,
                                                int expert, int init) {
    constexpr int BK = 32;
    __shared__ __align__(16) __bf16 As[128 * BK];
    __shared__ __align__(16) __bf16 Bs[128 * BK];
    const int tid = threadIdx.x;
    const int wave = tid >> 6, lane = tid & 63;
    const int r16 = lane & 15, quad = lane >> 4;
    const int m0 = blockIdx.y * 128, n0 = blockIdx.x * 128;
    const int wm = (wave & 1) * 64, wn = (wave >> 1) * 64;

    // Staging: tile row = 32 bf16 = 4 chunks of 16B. chunk c -> row c>>2, col8 c&3.
    const int c0 = tid, c1 = tid + 256;
    const __bf16* Ag0 = A + (size_t)(m0 + (c0 >> 2)) * K + (c0 & 3) * 8;
    const __bf16* Ag1 = A + (size_t)(m0 + (c1 >> 2)) * K + (c1 & 3) * 8;
    const __bf16* Bg0 = B + (size_t)(n0 + (c0 >> 2)) * K + (c0 & 3) * 8;
    const __bf16* Bg1 = B + (size_t)(n0 + (c1 >> 2)) * K + (c1 & 3) * 8;
    // LDS dest is wave-uniform base + lane*16B (global_load_lds semantics).
    __bf16* sA0 = &As[(wave * 64) * 8];
    __bf16* sA1 = &As[(256 + wave * 64) * 8];
    __bf16* sB0 = &Bs[(wave * 64) * 8];
    __bf16* sB1 = &Bs[(256 + wave * 64) * 8];

    f32x4 acc[4][4] = {};

    for (int k0 = 0; k0 < K; k0 += BK) {
        gl_lds16(Ag0 + k0, sA0);
        gl_lds16(Ag1 + k0, sA1);
        gl_lds16(Bg0 + k0, sB0);
        gl_lds16(Bg1 + k0, sB1);
        __syncthreads();
        bf16x8 af[4], bfr[4];
#pragma unroll
        for (int i = 0; i < 4; i++)
            af[i] = *(const bf16x8*)&As[(wm + i * 16 + r16) * BK + quad * 8];
#pragma unroll
        for (int i = 0; i < 4; i++)
            bfr[i] = *(const bf16x8*)&Bs[(wn + i * 16 + r16) * BK + quad * 8];
#pragma unroll
        for (int mi = 0; mi < 4; mi++)
#pragma unroll
            for (int ni = 0; ni < 4; ni++)
                acc[mi][ni] = __builtin_amdgcn_mfma_f32_16x16x32_bf16(
                    af[mi], bfr[ni], acc[mi][ni], 0, 0, 0);
        __syncthreads();
    }

    // Epilogue. D layout: row(m) = quad*4 + reg, col(n) = lane&15.
    const int colBase = n0 + wn + r16;
    if (MODE == 0) {
#pragma unroll
        for (int mi = 0; mi < 4; mi++) {
            const int rowBase = m0 + wm + mi * 16 + quad * 4;
#pragma unroll
            for (int ni = 0; ni < 4; ni++) {
                const int col = colBase + ni * 16;
                const float bv = bias[col];
#pragma unroll
                for (int r = 0; r < 4; r++) {
                    float xv = acc[mi][ni][r] + bv;
                    float gv = 0.5f * xv * (1.0f + erff(xv * 0.70710678118654752f));
                    Hout[(size_t)(rowBase + r) * ODIM + col] = (__bf16)gv;
                }
            }
        }
    } else {
#pragma unroll
        for (int mi = 0; mi < 4; mi++) {
            const int rowBase = m0 + wm + mi * 16 + quad * 4;
            float g[4];
#pragma unroll
            for (int r = 0; r < 4; r++) g[r] = gates[(rowBase + r) * NEXP + expert];
#pragma unroll
            for (int ni = 0; ni < 4; ni++) {
                const int col = colBase + ni * 16;
                const float bv = bias[col];
#pragma unroll
                for (int r = 0; r < 4; r++) {
                    float v = g[r] * (acc[mi][ni][r] + bv);
                    size_t o = (size_t)(rowBase + r) * ODIM + col;
                    if (init) Fout[o] = v;
                    else      Fout[o] += v;
                }
            }
        }
    }
}

// ---------------- in-place LayerNorm over last dim (4096) ----------------
__global__ __launch_bounds__(256) void ln_kernel(float* __restrict__ out,
                                                 const float* __restrict__ lw,
                                                 const float* __restrict__ lb,
                                                 const float* __restrict__ gsp) {
    const int t = blockIdx.x;
    float* row = out + (size_t)t * ODIM;
    const float gs = gsp[0];
    float4 v[4];
    float s = 0.f, ss = 0.f;
#pragma unroll
    for (int i = 0; i < 4; i++) {
        float4 a = ((const float4*)row)[threadIdx.x + i * 256];
        a.x *= gs; a.y *= gs; a.z *= gs; a.w *= gs;
        v[i] = a;
        s += a.x + a.y + a.z + a.w;
        ss += a.x * a.x + a.y * a.y + a.z * a.z + a.w * a.w;
    }
#pragma unroll
    for (int off = 32; off; off >>= 1) {
        s += __shfl_xor(s, off);
        ss += __shfl_xor(ss, off);
    }
    __shared__ float rs[4], rss[4];
    const int wave = threadIdx.x >> 6, lane = threadIdx.x & 63;
    if (lane == 0) { rs[wave] = s; rss[wave] = ss; }
    __syncthreads();
    s = rs[0] + rs[1] + rs[2] + rs[3];
    ss = rss[0] + rss[1] + rss[2] + rss[3];
    const float mu = s * (1.0f / ODIM);
    const float var = ss * (1.0f / ODIM) - mu * mu;
    const float inv = 1.0f / sqrtf(var + 1e-5f);
#pragma unroll
    for (int i = 0; i < 4; i++) {
        const int c4 = threadIdx.x + i * 256;
        float4 w4 = ((const float4*)lw)[c4];
        float4 b4 = ((const float4*)lb)[c4];
        float4 o;
        o.x = (v[i].x - mu) * inv * w4.x + b4.x;
        o.y = (v[i].y - mu) * inv * w4.y + b4.y;
        o.z = (v[i].z - mu) * inv * w4.z + b4.z;
        o.w = (v[i].w - mu) * inv * w4.w + b4.w;
        ((float4*)row)[c4] = o;
    }
}

extern "C" void kernel_launch(void* const* d_in, const int* in_sizes, int n_in,
                              void* d_out, int out_size, void* d_ws, size_t ws_size,
                              hipStream_t stream) {
    const float* x   = (const float*)d_in[0];
    const float* Wg  = (const float*)d_in[1];
    const float* bg  = (const float*)d_in[2];
    const float* W1  = (const float*)d_in[3];
    const float* b1  = (const float*)d_in[4];
    const float* W2  = (const float*)d_in[5];
    const float* b2  = (const float*)d_in[6];
    const float* lnw = (const float*)d_in[7];
    const float* lnb = (const float*)d_in[8];
    const float* gsc = (const float*)d_in[9];
    float* out = (float*)d_out;

    // Workspace layout (~240 MB)
    char* w = (char*)d_ws;
    __bf16* Xb  = (__bf16*)w;                          // T*D bf16      = 16 MB
    __bf16* W1T = Xb + (size_t)T_TOK * DDIM;           // E*O*D bf16    = 32 MB
    __bf16* W2T = W1T + (size_t)NEXP * ODIM * DDIM;    // E*O*O bf16    = 128 MB
    __bf16* H   = W2T + (size_t)NEXP * ODIM * ODIM;    // T*O bf16      = 64 MB
    float* gates = (float*)(H + (size_t)T_TOK * ODIM); // T*4 fp32      = 128 KB

    cvt_bf16_vec<<<(T_TOK * DDIM / 4) / 256, 256, 0, stream>>>(x, Xb, T_TOK * DDIM / 4);
    dim3 tb(32, 8);
    transpose_cvt<<<dim3(ODIM / 32, DDIM / 32, NEXP), tb, 0, stream>>>(W1, W1T, DDIM, ODIM);
    transpose_cvt<<<dim3(ODIM / 32, ODIM / 32, NEXP), tb, 0, stream>>>(W2, W2T, ODIM, ODIM);
    router_kernel<<<T_TOK / 4, 256, 0, stream>>>(x, Wg, bg, gates);

    for (int e = 0; e < NEXP; e++) {
        moe_gemm<0><<<dim3(ODIM / 128, T_TOK / 128), 256, 0, stream>>>(
            Xb, W1T + (size_t)e * ODIM * DDIM, DDIM, b1 + e * ODIM,
            H, nullptr, nullptr, e, 0);
        moe_gemm<1><<<dim3(ODIM / 128, T_TOK / 128), 256, 0, stream>>>(
            H, W2T + (size_t)e * ODIM * ODIM, ODIM, b2 + e * ODIM,
            nullptr, out, gates, e, (e == 0) ? 1 : 0);
    }
    ln_kernel<<<T_TOK, 256, 0, stream>>>(out, lnw, lnb, gsc);
}

// Round 2
// 2045.338 us; speedup vs baseline: 1.3319x; 1.3319x over previous
//
#include <hip/hip_runtime.h>
#include <cmath>

// ---------------------------------------------------------------------------
// MoEProjector: router(softmax,top2) -> per-expert [Linear -> GELU -> Linear]
// -> gate-weighted combine -> *gate_scale -> LayerNorm.
// T=8192 tokens, D=1024, O=4096, E=4, top-2.
// R2: top-2 sparse gathered GEMMs (halve FLOPs) + tanh-GELU epilogue.
// GEMM core: m97 structure (128x128 tile, BK=32, global_load_lds width=16).
// ---------------------------------------------------------------------------

typedef float f32x4 __attribute__((ext_vector_type(4)));
typedef __bf16 bf16x8 __attribute__((ext_vector_type(8)));
typedef __bf16 bf16x4 __attribute__((ext_vector_type(4)));

#define T_TOK 8192
#define DDIM 1024
#define ODIM 4096
#define NEXP 4

__device__ __forceinline__ void gl_lds16(const void* g, void* l) {
    __builtin_amdgcn_global_load_lds(
        (const __attribute__((address_space(1))) void*)g,
        (__attribute__((address_space(3))) void*)l, 16, 0, 0);
}

// ---------------- x fp32 -> bf16 (vectorized) ----------------
__global__ __launch_bounds__(256) void cvt_bf16_vec(const float* __restrict__ in,
                                                    __bf16* __restrict__ out, int n4) {
    int i = blockIdx.x * 256 + threadIdx.x;
    if (i >= n4) return;
    float4 v = ((const float4*)in)[i];
    bf16x4 o = { (__bf16)v.x, (__bf16)v.y, (__bf16)v.z, (__bf16)v.w };
    ((bf16x4*)out)[i] = o;
}

// ------------- W [R,C] fp32 -> Wt [C,R] bf16, per expert (z) -------------
__global__ __launch_bounds__(256) void transpose_cvt(const float* __restrict__ in,
                                                     __bf16* __restrict__ out,
                                                     int R, int C) {
    __shared__ float tile[32][33];
    const size_t eoff = (size_t)blockIdx.z * R * C;
    const float* ip = in + eoff;
    __bf16* op = out + eoff;
    const int c0 = blockIdx.x * 32, r0 = blockIdx.y * 32;
    const int tx = threadIdx.x, ty = threadIdx.y;  // 32 x 8
#pragma unroll
    for (int i = 0; i < 4; i++)
        tile[ty + i * 8][tx] = ip[(size_t)(r0 + ty + i * 8) * C + c0 + tx];
    __syncthreads();
#pragma unroll
    for (int i = 0; i < 4; i++)
        op[(size_t)(c0 + ty + i * 8) * R + r0 + tx] = (__bf16)tile[tx][ty + i * 8];
}

// -------- router: fp32 logits -> softmax -> top2 -> compacted lists --------
__global__ __launch_bounds__(256) void router_kernel(const float* __restrict__ x,
                                                     const float* __restrict__ Wg,
                                                     const float* __restrict__ bg,
                                                     int* __restrict__ counts,
                                                     int* __restrict__ perm,
                                                     float* __restrict__ wlist) {
    const int wave = threadIdx.x >> 6, lane = threadIdx.x & 63;
    const int t = blockIdx.x * 4 + wave;
    const float* xr = x + (size_t)t * DDIM;
    float a0 = 0.f, a1 = 0.f, a2 = 0.f, a3 = 0.f;
    const float4* Wg4 = (const float4*)Wg;  // Wg[d*4 + e] contiguous over e
    for (int d = lane; d < DDIM; d += 64) {
        float xv = xr[d];
        float4 w = Wg4[d];
        a0 += xv * w.x; a1 += xv * w.y; a2 += xv * w.z; a3 += xv * w.w;
    }
#pragma unroll
    for (int off = 32; off; off >>= 1) {
        a0 += __shfl_xor(a0, off); a1 += __shfl_xor(a1, off);
        a2 += __shfl_xor(a2, off); a3 += __shfl_xor(a3, off);
    }
    if (lane == 0) {
        float l[4] = {a0 + bg[0], a1 + bg[1], a2 + bg[2], a3 + bg[3]};
        float mx = fmaxf(fmaxf(l[0], l[1]), fmaxf(l[2], l[3]));
        float p[4], s = 0.f;
#pragma unroll
        for (int e = 0; e < 4; e++) { p[e] = expf(l[e] - mx); s += p[e]; }
#pragma unroll
        for (int e = 0; e < 4; e++) p[e] /= s;
        int e1 = 0;  // argmax, lowest index on ties (strict >)
#pragma unroll
        for (int e = 1; e < 4; e++) if (p[e] > p[e1]) e1 = e;
        int e2 = (e1 == 0) ? 1 : 0;
#pragma unroll
        for (int e = 0; e < 4; e++) if (e != e1 && p[e] > p[e2]) e2 = e;
        const float inv = 1.0f / (p[e1] + p[e2]);
        int pos1 = atomicAdd(&counts[e1], 1);
        perm[e1 * T_TOK + pos1] = t;
        wlist[e1 * T_TOK + pos1] = p[e1] * inv;
        int pos2 = atomicAdd(&counts[e2], 1);
        perm[e2 * T_TOK + pos2] = t;
        wlist[e2 * T_TOK + pos2] = p[e2] * inv;
    }
}

// ------- GEMM C[M,N] = A[M,K] @ B^T[N,K]  (bf16 in, fp32 acc), gathered -----
// MODE 0: A rows gathered via perm (tokens);  H[i] = gelu(acc + b1) -> bf16
// MODE 1: A = H dense rows;  out[perm[i]] += wlist[i] * (acc + b2)  (fp32 RMW)
template <int MODE, int KDIM>
__global__ __launch_bounds__(256) void moe_gemm(const __bf16* __restrict__ A,
                                                const __bf16* __restrict__ B,
                                                const float* __restrict__ bias,
                                                __bf16* __restrict__ Hout,
                                                float* __restrict__ Fout,
                                                const int* __restrict__ perm,
                                                const float* __restrict__ wlist,
                                                const int* __restrict__ countp) {
    constexpr int BK = 32;
    __shared__ __align__(16) __bf16 As[128 * BK];
    __shared__ __align__(16) __bf16 Bs[128 * BK];
    const int count = *countp;
    const int m0 = blockIdx.y * 128;
    if (m0 >= count) return;  // block-uniform early exit
    const int tid = threadIdx.x;
    const int wave = tid >> 6, lane = tid & 63;
    const int r16 = lane & 15, quad = lane >> 4;
    const int n0 = blockIdx.x * 128;
    const int wm = (wave & 1) * 64, wn = (wave >> 1) * 64;

    // Staging: tile row = 32 bf16 = 4 chunks of 16B. chunk c -> row c>>2, col8 c&3.
    const int c0 = tid, c1 = tid + 256;
    const __bf16 *Ag0, *Ag1;
    if (MODE == 0) {  // gather token rows through perm (padding rows -> token 0)
        Ag0 = A + (size_t)perm[m0 + (c0 >> 2)] * KDIM + (c0 & 3) * 8;
        Ag1 = A + (size_t)perm[m0 + (c1 >> 2)] * KDIM + (c1 & 3) * 8;
    } else {
        Ag0 = A + (size_t)(m0 + (c0 >> 2)) * KDIM + (c0 & 3) * 8;
        Ag1 = A + (size_t)(m0 + (c1 >> 2)) * KDIM + (c1 & 3) * 8;
    }
    const __bf16* Bg0 = B + (size_t)(n0 + (c0 >> 2)) * KDIM + (c0 & 3) * 8;
    const __bf16* Bg1 = B + (size_t)(n0 + (c1 >> 2)) * KDIM + (c1 & 3) * 8;
    // LDS dest is wave-uniform base + lane*16B (global_load_lds semantics).
    __bf16* sA0 = &As[(wave * 64) * 8];
    __bf16* sA1 = &As[(256 + wave * 64) * 8];
    __bf16* sB0 = &Bs[(wave * 64) * 8];
    __bf16* sB1 = &Bs[(256 + wave * 64) * 8];

    f32x4 acc[4][4] = {};

    for (int k0 = 0; k0 < KDIM; k0 += BK) {
        gl_lds16(Ag0 + k0, sA0);
        gl_lds16(Ag1 + k0, sA1);
        gl_lds16(Bg0 + k0, sB0);
        gl_lds16(Bg1 + k0, sB1);
        __syncthreads();
        bf16x8 af[4], bfr[4];
#pragma unroll
        for (int i = 0; i < 4; i++)
            af[i] = *(const bf16x8*)&As[(wm + i * 16 + r16) * BK + quad * 8];
#pragma unroll
        for (int i = 0; i < 4; i++)
            bfr[i] = *(const bf16x8*)&Bs[(wn + i * 16 + r16) * BK + quad * 8];
#pragma unroll
        for (int mi = 0; mi < 4; mi++)
#pragma unroll
            for (int ni = 0; ni < 4; ni++)
                acc[mi][ni] = __builtin_amdgcn_mfma_f32_16x16x32_bf16(
                    af[mi], bfr[ni], acc[mi][ni], 0, 0, 0);
        __syncthreads();
    }

    // Epilogue. D layout: row(m) = quad*4 + reg, col(n) = lane&15.
    const int colBase = n0 + wn + r16;
    if (MODE == 0) {
#pragma unroll
        for (int mi = 0; mi < 4; mi++) {
            const int rowBase = m0 + wm + mi * 16 + quad * 4;
#pragma unroll
            for (int ni = 0; ni < 4; ni++) {
                const int col = colBase + ni * 16;
                const float bv = bias[col];
#pragma unroll
                for (int r = 0; r < 4; r++) {
                    if (rowBase + r < count) {
                        float xv = acc[mi][ni][r] + bv;
                        // tanh-form GELU: x * sigmoid(1.59577*x*(1+0.044715*x^2))
                        float u = 1.5957691216057308f * xv * (1.0f + 0.044715f * xv * xv);
                        float gv = xv * __builtin_amdgcn_rcpf(1.0f + __expf(-u));
                        Hout[(size_t)(rowBase + r) * ODIM + col] = (__bf16)gv;
                    }
                }
            }
        }
    } else {
#pragma unroll
        for (int mi = 0; mi < 4; mi++) {
            const int rowBase = m0 + wm + mi * 16 + quad * 4;
            int tok[4]; float g[4]; bool ok[4];
#pragma unroll
            for (int r = 0; r < 4; r++) {
                const int i = rowBase + r;
                ok[r] = (i < count);
                tok[r] = ok[r] ? perm[i] : 0;
                g[r] = ok[r] ? wlist[i] : 0.f;
            }
#pragma unroll
            for (int ni = 0; ni < 4; ni++) {
                const int col = colBase + ni * 16;
                const float bv = bias[col];
#pragma unroll
                for (int r = 0; r < 4; r++) {
                    if (ok[r]) {
                        float v = g[r] * (acc[mi][ni][r] + bv);
                        Fout[(size_t)tok[r] * ODIM + col] += v;
                    }
                }
            }
        }
    }
}

// ---------------- in-place LayerNorm over last dim (4096) ----------------
__global__ __launch_bounds__(256) void ln_kernel(float* __restrict__ out,
                                                 const float* __restrict__ lw,
                                                 const float* __restrict__ lb,
                                                 const float* __restrict__ gsp) {
    const int t = blockIdx.x;
    float* row = out + (size_t)t * ODIM;
    const float gs = gsp[0];
    float4 v[4];
    float s = 0.f, ss = 0.f;
#pragma unroll
    for (int i = 0; i < 4; i++) {
        float4 a = ((const float4*)row)[threadIdx.x + i * 256];
        a.x *= gs; a.y *= gs; a.z *= gs; a.w *= gs;
        v[i] = a;
        s += a.x + a.y + a.z + a.w;
        ss += a.x * a.x + a.y * a.y + a.z * a.z + a.w * a.w;
    }
#pragma unroll
    for (int off = 32; off; off >>= 1) {
        s += __shfl_xor(s, off);
        ss += __shfl_xor(ss, off);
    }
    __shared__ float rs[4], rss[4];
    const int wave = threadIdx.x >> 6, lane = threadIdx.x & 63;
    if (lane == 0) { rs[wave] = s; rss[wave] = ss; }
    __syncthreads();
    s = rs[0] + rs[1] + rs[2] + rs[3];
    ss = rss[0] + rss[1] + rss[2] + rss[3];
    const float mu = s * (1.0f / ODIM);
    const float var = ss * (1.0f / ODIM) - mu * mu;
    const float inv = 1.0f / sqrtf(var + 1e-5f);
#pragma unroll
    for (int i = 0; i < 4; i++) {
        const int c4 = threadIdx.x + i * 256;
        float4 w4 = ((const float4*)lw)[c4];
        float4 b4 = ((const float4*)lb)[c4];
        float4 o;
        o.x = (v[i].x - mu) * inv * w4.x + b4.x;
        o.y = (v[i].y - mu) * inv * w4.y + b4.y;
        o.z = (v[i].z - mu) * inv * w4.z + b4.z;
        o.w = (v[i].w - mu) * inv * w4.w + b4.w;
        ((float4*)row)[c4] = o;
    }
}

extern "C" void kernel_launch(void* const* d_in, const int* in_sizes, int n_in,
                              void* d_out, int out_size, void* d_ws, size_t ws_size,
                              hipStream_t stream) {
    const float* x   = (const float*)d_in[0];
    const float* Wg  = (const float*)d_in[1];
    const float* bg  = (const float*)d_in[2];
    const float* W1  = (const float*)d_in[3];
    const float* b1  = (const float*)d_in[4];
    const float* W2  = (const float*)d_in[5];
    const float* b2  = (const float*)d_in[6];
    const float* lnw = (const float*)d_in[7];
    const float* lnb = (const float*)d_in[8];
    const float* gsc = (const float*)d_in[9];
    float* out = (float*)d_out;

    // Workspace layout (~240 MB)
    char* w = (char*)d_ws;
    __bf16* Xb  = (__bf16*)w;                          // T*D bf16      = 16 MB
    __bf16* W1T = Xb + (size_t)T_TOK * DDIM;           // E*O*D bf16    = 32 MB
    __bf16* W2T = W1T + (size_t)NEXP * ODIM * DDIM;    // E*O*O bf16    = 128 MB
    __bf16* H   = W2T + (size_t)NEXP * ODIM * ODIM;    // T*O bf16      = 64 MB (per-expert reuse)
    int*   counts = (int*)(H + (size_t)T_TOK * ODIM);  // E ints
    int*   perm   = counts + NEXP;                     // E*T ints
    float* wlist  = (float*)(perm + NEXP * T_TOK);     // E*T floats

    // Zero routing lists (perm padding -> token 0) and the output accumulator.
    hipMemsetAsync(counts, 0, (NEXP + 2 * NEXP * T_TOK) * sizeof(int) , stream);
    hipMemsetAsync(out, 0, (size_t)T_TOK * ODIM * sizeof(float), stream);

    cvt_bf16_vec<<<(T_TOK * DDIM / 4) / 256, 256, 0, stream>>>(x, Xb, T_TOK * DDIM / 4);
    dim3 tb(32, 8);
    transpose_cvt<<<dim3(ODIM / 32, DDIM / 32, NEXP), tb, 0, stream>>>(W1, W1T, DDIM, ODIM);
    transpose_cvt<<<dim3(ODIM / 32, ODIM / 32, NEXP), tb, 0, stream>>>(W2, W2T, ODIM, ODIM);
    router_kernel<<<T_TOK / 4, 256, 0, stream>>>(x, Wg, bg, counts, perm, wlist);

    for (int e = 0; e < NEXP; e++) {
        moe_gemm<0, DDIM><<<dim3(ODIM / 128, T_TOK / 128), 256, 0, stream>>>(
            Xb, W1T + (size_t)e * ODIM * DDIM, b1 + e * ODIM,
            H, nullptr, perm + e * T_TOK, nullptr, counts + e);
        moe_gemm<1, ODIM><<<dim3(ODIM / 128, T_TOK / 128), 256, 0, stream>>>(
            H, W2T + (size_t)e * ODIM * ODIM, b2 + e * ODIM,
            nullptr, out, perm + e * T_TOK, wlist + e * T_TOK, counts + e);
    }
    ln_kernel<<<T_TOK, 256, 0, stream>>>(out, lnw, lnb, gsc);
}